// Round 2
// baseline (747.614 us; speedup 1.0000x reference)
//
#include <hip/hip_runtime.h>

#define T_LEN   262144
#define NV      20
#define NE      30
#define NH      40
#define NG      160                    // 4*NH
#define CHUNK   512
#define WARM    128
#define SPC     (WARM + CHUNK)         // 640
#define NBLK    (T_LEN / CHUNK)        // 512
#define SS      32                     // steps per super-step (ring batch)
#define NSS     (SPC / SS)             // 20
#define WUSS    (WARM / SS)            // 4
#define NTHR    192

__device__ __forceinline__ float sig_(float x) {
    x = fminf(fmaxf(x, -30.f), 30.f);
    return __fdividef(1.f, 1.f + __expf(-x));
}
__device__ __forceinline__ float tanh_(float x) {
    x = fminf(fmaxf(x, -15.f), 15.f);
    float e = __expf(2.f * x);
    return __fdividef(e - 1.f, e + 1.f);
}

// Wave roles per block (192 thr = 3 waves):
//   wave 0: forward cell, lane k holds h_k,c_k + W_hh1 rows (i,f,g,o) for unit k
//   wave 1: backward cell, same for W_hh2
//   wave 2: logits — consumes 32-step h batches from an LDS ring, one barrier/32 steps
extern "C" __global__ void __launch_bounds__(NTHR, 1)
bilstm_kernel(const int* __restrict__ tokens,
              const float* __restrict__ embed,
              const float* __restrict__ W_ih1, const float* __restrict__ W_hh1,
              const float* __restrict__ b_ih1, const float* __restrict__ b_hh1,
              const float* __restrict__ W_ih2, const float* __restrict__ W_hh2,
              const float* __restrict__ b_ih2, const float* __restrict__ b_hh2,
              const float* __restrict__ W_l1,  const float* __restrict__ b_l1,
              const float* __restrict__ W_l2,  const float* __restrict__ b_l2,
              float* __restrict__ out)
{
    __shared__ __align__(16) float tab[2 * NV * NH * 4];   // [d][v][k][gate] x-pre lookup
    __shared__ __align__(16) float ring[2][2][SS][NH];     // [parity][d][sl][k]
    __shared__ __align__(16) float embS[NV * NE];
    __shared__ int tokS[2][SPC];

    const int tid  = threadIdx.x;
    const int wave = tid >> 6;
    const int lane = tid & 63;
    const int a    = blockIdx.x * CHUNK;

    // ---- stage embed + tokens ----
    for (int p = tid; p < NV * NE; p += NTHR) embS[p] = embed[p];
    for (int p = tid; p < SPC; p += NTHR) {
        int t = a - WARM + p;
        if (t >= 0) {
            tokS[0][p] = tokens[t];
            tokS[1][p] = tokens[T_LEN - 1 - t];
        }
    }
    __syncthreads();

    // ---- build x-pre tables: tab[((d*NV+v)*NH+k)*4+g] = emb[v]·W_ih[g*NH+k] + b_ih+b_hh ----
    for (int p = tid; p < 2 * NV * NG; p += NTHR) {
        int g = p & 3, r = p >> 2;
        int k = r % NH, q = r / NH;
        int v = q % NV, dd = q / NV;
        const float* Wih = dd ? W_ih2 : W_ih1;
        const float* bi  = dd ? b_ih2 : b_ih1;
        const float* bh  = dd ? b_hh2 : b_hh1;
        int j = g * NH + k;
        float acc = bi[j] + bh[j];
        #pragma unroll
        for (int e = 0; e < NE; ++e) acc += embS[v * NE + e] * Wih[j * NE + e];
        tab[p] = acc;
    }

    // ---- per-wave weight registers ----
    const bool isCell = (wave < 2);
    const int  dir    = wave;                    // cell waves only
    const int  kk     = (lane < NH) ? lane : NH - 1;

    float wi[NH], wf[NH], wg[NH], wo[NH];        // cell: W_hh rows; logit wave reuses wi
    float lb = 0.f;
    if (isCell) {
        const float* Whh = dir ? W_hh2 : W_hh1;
        #pragma unroll
        for (int q = 0; q < NH / 4; ++q) {
            float4 t0 = ((const float4*)(Whh + (0*NH+kk)*NH))[q];
            float4 t1 = ((const float4*)(Whh + (1*NH+kk)*NH))[q];
            float4 t2 = ((const float4*)(Whh + (2*NH+kk)*NH))[q];
            float4 t3 = ((const float4*)(Whh + (3*NH+kk)*NH))[q];
            wi[4*q]=t0.x; wi[4*q+1]=t0.y; wi[4*q+2]=t0.z; wi[4*q+3]=t0.w;
            wf[4*q]=t1.x; wf[4*q+1]=t1.y; wf[4*q+2]=t1.z; wf[4*q+3]=t1.w;
            wg[4*q]=t2.x; wg[4*q+1]=t2.y; wg[4*q+2]=t2.z; wg[4*q+3]=t2.w;
            wo[4*q]=t3.x; wo[4*q+1]=t3.y; wo[4*q+2]=t3.z; wo[4*q+3]=t3.w;
        }
    } else {
        int half = lane >> 5, v = lane & 31;
        int vv   = (v < NV) ? v : NV - 1;
        const float* Wl = half ? W_l2 : W_l1;
        #pragma unroll
        for (int q = 0; q < NH / 4; ++q) {
            float4 t0 = ((const float4*)(Wl + vv*NH))[q];
            wi[4*q]=t0.x; wi[4*q+1]=t0.y; wi[4*q+2]=t0.z; wi[4*q+3]=t0.w;
        }
        if (!half) lb = b_l1[vv] + b_l2[vv];
    }
    __syncthreads();   // tab + tokS ready

    // ---- cell init + first x-pre prefetch ----
    const int cell_ss0 = (a < WARM) ? WUSS : 0;   // block 0 starts at s=WARM exactly
    float h = 0.f, c = 0.f;
    float x0 = 0.f, x1 = 0.f, x2 = 0.f, x3 = 0.f;
    if (isCell) {
        int tk = tokS[dir][cell_ss0 * SS];
        float4 xv = *(const float4*)&tab[((dir*NV + tk)*NH + kk)*4];
        x0 = xv.x; x1 = xv.y; x2 = xv.z; x3 = xv.w;
    }

    // ---- main loop: NSS super-steps of SS steps + 1 logit flush ----
    for (int ss = 0; ss <= NSS; ++ss) {
        if (isCell && ss >= cell_ss0 && ss < NSS) {
            const int sbase = ss * SS;
            #pragma unroll 1
            for (int sl = 0; sl < SS; ++sl) {
                const int s = sbase + sl;
                float ai = 0.f, af = 0.f, ag = 0.f, ao = 0.f;
                const int hb = __float_as_int(h);
                #pragma unroll
                for (int m = 0; m < NH; ++m) {
                    float hm = __int_as_float(__builtin_amdgcn_readlane(hb, m));
                    ai = fmaf(hm, wi[m], ai);
                    af = fmaf(hm, wf[m], af);
                    ag = fmaf(hm, wg[m], ag);
                    ao = fmaf(hm, wo[m], ao);
                }
                ai += x0; af += x1; ag += x2; ao += x3;
                if (s + 1 < SPC) {               // prefetch next x-pre (hidden behind activations)
                    int tk = tokS[dir][s + 1];
                    float4 xv = *(const float4*)&tab[((dir*NV + tk)*NH + kk)*4];
                    x0 = xv.x; x1 = xv.y; x2 = xv.z; x3 = xv.w;
                }
                float I = sig_(ai), F = sig_(af), G = tanh_(ag), O = sig_(ao);
                c = fmaf(F, c, I * G);
                h = O * tanh_(c);
                if (lane < NH) ring[ss & 1][dir][sl][lane] = h;
            }
        }
        if (!isCell && ss > WUSS && ss <= NSS) {
            const int b = ss - 1, par = b & 1;
            const int half = lane >> 5, v = lane & 31;
            #pragma unroll 1
            for (int sl = 0; sl < SS; ++sl) {
                const float* hr = ring[par][half][sl];
                float acc = 0.f;
                #pragma unroll
                for (int q = 0; q < NH / 4; ++q) {
                    float4 hv = ((const float4*)hr)[q];
                    acc += hv.x*wi[4*q] + hv.y*wi[4*q+1] + hv.z*wi[4*q+2] + hv.w*wi[4*q+3];
                }
                float oth = __shfl_xor(acc, 32, 64);
                if (half == 0 && v < NV) {
                    int trow = a + b * SS + sl - WARM;
                    out[(size_t)trow * NV + v] = acc + oth + lb;
                }
            }
        }
        __syncthreads();
    }
}

extern "C" void kernel_launch(void* const* d_in, const int* in_sizes, int n_in,
                              void* d_out, int out_size, void* d_ws, size_t ws_size,
                              hipStream_t stream)
{
    const int*   tokens = (const int*)  d_in[0];
    const float* embed  = (const float*)d_in[1];
    const float* W_ih1  = (const float*)d_in[2];
    const float* W_hh1  = (const float*)d_in[3];
    const float* b_ih1  = (const float*)d_in[4];
    const float* b_hh1  = (const float*)d_in[5];
    const float* W_ih2  = (const float*)d_in[6];
    const float* W_hh2  = (const float*)d_in[7];
    const float* b_ih2  = (const float*)d_in[8];
    const float* b_hh2  = (const float*)d_in[9];
    const float* W_l1   = (const float*)d_in[10];
    const float* b_l1   = (const float*)d_in[11];
    const float* W_l2   = (const float*)d_in[12];
    const float* b_l2   = (const float*)d_in[13];
    float* outp = (float*)d_out;

    hipLaunchKernelGGL(bilstm_kernel, dim3(NBLK), dim3(NTHR), 0, stream,
                       tokens, embed, W_ih1, W_hh1, b_ih1, b_hh1,
                       W_ih2, W_hh2, b_ih2, b_hh2, W_l1, b_l1, W_l2, b_l2, outp);
}

// Round 3
// 641.788 us; speedup vs baseline: 1.1649x; 1.1649x over previous
//
#include <hip/hip_runtime.h>

#define T_LEN   262144
#define NV      20
#define NE      30
#define NH      40
#define NG      160                    // 4*NH
#define CHUNK   512
#define WARM    64
#define SPC     (WARM + CHUNK)         // 576
#define NBLK    (T_LEN / CHUNK)        // 512
#define SS      32                     // steps per super-step
#define NSS     (SPC / SS)             // 18
#define WUSS    (WARM / SS)            // 2
#define NTHR    192

__device__ __forceinline__ float sig_(float x) {
    x = fminf(fmaxf(x, -30.f), 30.f);
    return __fdividef(1.f, 1.f + __expf(-x));
}
__device__ __forceinline__ float tanh_(float x) {
    x = fminf(fmaxf(x, -15.f), 15.f);
    float e = __expf(2.f * x);
    return __fdividef(e - 1.f, e + 1.f);
}
__device__ __forceinline__ float rl_(int v, int l) {
    return __int_as_float(__builtin_amdgcn_readlane(v, l));
}

// 10 named float4 per gate -> guaranteed VGPR residency (no indexed arrays).
#define DECL10(V) float4 V##0, V##1, V##2, V##3, V##4, V##5, V##6, V##7, V##8, V##9
#define LOAD10(V, P) do { const float4* _p = (const float4*)(P); \
    V##0=_p[0]; V##1=_p[1]; V##2=_p[2]; V##3=_p[3]; V##4=_p[4]; \
    V##5=_p[5]; V##6=_p[6]; V##7=_p[7]; V##8=_p[8]; V##9=_p[9]; } while(0)

#define ACCQ(Q) do { \
    const float e0 = rl_(hb, 4*Q+0); \
    const float e1 = rl_(hb, 4*Q+1); \
    const float e2 = rl_(hb, 4*Q+2); \
    const float e3 = rl_(hb, 4*Q+3); \
    ai = fmaf(e0, wi##Q.x, ai); af = fmaf(e0, wf##Q.x, af); \
    ag = fmaf(e0, wg##Q.x, ag); ao = fmaf(e0, wo##Q.x, ao); \
    ai = fmaf(e1, wi##Q.y, ai); af = fmaf(e1, wf##Q.y, af); \
    ag = fmaf(e1, wg##Q.y, ag); ao = fmaf(e1, wo##Q.y, ao); \
    ai = fmaf(e2, wi##Q.z, ai); af = fmaf(e2, wf##Q.z, af); \
    ag = fmaf(e2, wg##Q.z, ag); ao = fmaf(e2, wo##Q.z, ao); \
    ai = fmaf(e3, wi##Q.w, ai); af = fmaf(e3, wf##Q.w, af); \
    ag = fmaf(e3, wg##Q.w, ag); ao = fmaf(e3, wo##Q.w, ao); \
} while(0)

#define LDOT(Q) do { float4 hv = hr[Q]; \
    acc0 = fmaf(hv.x, wi##Q.x, acc0); acc1 = fmaf(hv.y, wi##Q.y, acc1); \
    acc0 = fmaf(hv.z, wi##Q.z, acc0); acc1 = fmaf(hv.w, wi##Q.w, acc1); } while(0)

// Wave roles per block (192 thr = 3 waves):
//   wave 0/1: LSTM cell per direction — lane k holds h_k,c_k and W_hh rows for
//             unit k in 160 named-scalar VGPRs; h broadcast via v_readlane.
//   wave 2:   logits — consumes 32-step h batches from a double-buffered LDS
//             ring; one barrier per 32 steps.
extern "C" __global__ void __launch_bounds__(NTHR, 1)
bilstm_kernel(const int* __restrict__ tokens,
              const float* __restrict__ embed,
              const float* __restrict__ W_ih1, const float* __restrict__ W_hh1,
              const float* __restrict__ b_ih1, const float* __restrict__ b_hh1,
              const float* __restrict__ W_ih2, const float* __restrict__ W_hh2,
              const float* __restrict__ b_ih2, const float* __restrict__ b_hh2,
              const float* __restrict__ W_l1,  const float* __restrict__ b_l1,
              const float* __restrict__ W_l2,  const float* __restrict__ b_l2,
              float* __restrict__ out)
{
    __shared__ __align__(16) float tab[2 * NV * NH * 4];   // [d][v][k][gate]
    __shared__ __align__(16) float ring[2][2][SS][64];     // [parity][d][sl][lane]
    __shared__ __align__(16) float embS[NV * NE];
    __shared__ int tokS[2][SPC];

    const int tid  = threadIdx.x;
    const int wave = tid >> 6;
    const int lane = tid & 63;
    const int a    = blockIdx.x * CHUNK;

    // ---- stage embed + tokens ----
    for (int p = tid; p < NV * NE; p += NTHR) embS[p] = embed[p];
    for (int p = tid; p < SPC; p += NTHR) {
        int t = a - WARM + p;
        if (t >= 0) {
            tokS[0][p] = tokens[t];
            tokS[1][p] = tokens[T_LEN - 1 - t];
        }
    }
    __syncthreads();

    // ---- x-pre tables: tab[((d*NV+v)*NH+k)*4+g] = emb[v]·W_ih[g*NH+k] + b_ih+b_hh ----
    for (int p = tid; p < 2 * NV * NG; p += NTHR) {
        int g = p & 3, r = p >> 2;
        int k = r % NH, q = r / NH;
        int v = q % NV, dd = q / NV;
        const float* Wih = dd ? W_ih2 : W_ih1;
        const float* bi  = dd ? b_ih2 : b_ih1;
        const float* bh  = dd ? b_hh2 : b_hh1;
        int j = g * NH + k;
        float acc = bi[j] + bh[j];
        #pragma unroll
        for (int e = 0; e < NE; ++e) acc += embS[v * NE + e] * Wih[j * NE + e];
        tab[p] = acc;
    }

    // ---- per-wave weights in named registers ----
    const bool isCell = (wave < 2);
    const int  dir    = wave;
    const int  kk     = (lane < NH) ? lane : NH - 1;

    DECL10(wi); DECL10(wf); DECL10(wg); DECL10(wo);
    float lb = 0.f;
    if (isCell) {
        const float* Whh = dir ? W_hh2 : W_hh1;
        LOAD10(wi, Whh + (0 * NH + kk) * NH);
        LOAD10(wf, Whh + (1 * NH + kk) * NH);
        LOAD10(wg, Whh + (2 * NH + kk) * NH);
        LOAD10(wo, Whh + (3 * NH + kk) * NH);
        __builtin_amdgcn_s_setprio(1);           // cell waves are the critical path
    } else {
        int half = lane >> 5, v = lane & 31;
        int vv   = (v < NV) ? v : NV - 1;
        const float* Wl = half ? W_l2 : W_l1;
        LOAD10(wi, Wl + vv * NH);                // logit wave reuses wi names
        if (!half) lb = b_l1[vv] + b_l2[vv];
    }
    __syncthreads();   // tab + tokS ready

    // ---- cell init + first x-pre prefetch ----
    const int cell_ss0 = (a < WARM) ? WUSS : 0;  // block 0 starts exactly at s=WARM
    float h = 0.f, c = 0.f;
    float x0 = 0.f, x1 = 0.f, x2 = 0.f, x3 = 0.f;
    if (isCell) {
        int tk = tokS[dir][cell_ss0 * SS];
        float4 xv = *(const float4*)&tab[((dir * NV + tk) * NH + kk) * 4];
        x0 = xv.x; x1 = xv.y; x2 = xv.z; x3 = xv.w;
    }

    // ---- main loop: NSS super-steps of SS steps + 1 logit flush ----
    #pragma unroll 1
    for (int ss = 0; ss <= NSS; ++ss) {
        if (isCell && ss >= cell_ss0 && ss < NSS) {
            const int sbase = ss * SS;
            #pragma unroll 1
            for (int sl = 0; sl < SS; ++sl) {
                const int s  = sbase + sl;
                const int hb = __float_as_int(h);
                float ai = x0, af = x1, ag = x2, ao = x3;
                ACCQ(0); ACCQ(1); ACCQ(2); ACCQ(3); ACCQ(4);
                ACCQ(5); ACCQ(6); ACCQ(7); ACCQ(8); ACCQ(9);
                int sn = (s + 1 < SPC) ? s + 1 : SPC - 1;     // prefetch next x-pre
                int tk = tokS[dir][sn];
                float4 xv = *(const float4*)&tab[((dir * NV + tk) * NH + kk) * 4];
                x0 = xv.x; x1 = xv.y; x2 = xv.z; x3 = xv.w;
                float I = sig_(ai), F = sig_(af), G = tanh_(ag), O = sig_(ao);
                c = fmaf(F, c, I * G);
                h = O * tanh_(c);
                ring[ss & 1][dir][sl][lane] = h;              // padded: no lane guard
            }
        }
        if (!isCell && ss > WUSS && ss <= NSS) {
            const int b = ss - 1, par = b & 1;
            const int half = lane >> 5, v = lane & 31;
            #pragma unroll 1
            for (int sl = 0; sl < SS; ++sl) {
                const float4* hr = (const float4*)ring[par][half][sl];
                float acc0 = 0.f, acc1 = 0.f;
                LDOT(0); LDOT(1); LDOT(2); LDOT(3); LDOT(4);
                LDOT(5); LDOT(6); LDOT(7); LDOT(8); LDOT(9);
                float acc = acc0 + acc1;
                float oth = __shfl_xor(acc, 32, 64);
                if (half == 0 && v < NV) {
                    int trow = a + b * SS + sl - WARM;
                    out[(size_t)trow * NV + v] = acc + oth + lb;
                }
            }
        }
        __syncthreads();
    }
}

extern "C" void kernel_launch(void* const* d_in, const int* in_sizes, int n_in,
                              void* d_out, int out_size, void* d_ws, size_t ws_size,
                              hipStream_t stream)
{
    const int*   tokens = (const int*)  d_in[0];
    const float* embed  = (const float*)d_in[1];
    const float* W_ih1  = (const float*)d_in[2];
    const float* W_hh1  = (const float*)d_in[3];
    const float* b_ih1  = (const float*)d_in[4];
    const float* b_hh1  = (const float*)d_in[5];
    const float* W_ih2  = (const float*)d_in[6];
    const float* W_hh2  = (const float*)d_in[7];
    const float* b_ih2  = (const float*)d_in[8];
    const float* b_hh2  = (const float*)d_in[9];
    const float* W_l1   = (const float*)d_in[10];
    const float* b_l1   = (const float*)d_in[11];
    const float* W_l2   = (const float*)d_in[12];
    const float* b_l2   = (const float*)d_in[13];
    float* outp = (float*)d_out;

    hipLaunchKernelGGL(bilstm_kernel, dim3(NBLK), dim3(NTHR), 0, stream,
                       tokens, embed, W_ih1, W_hh1, b_ih1, b_hh1,
                       W_ih2, W_hh2, b_ih2, b_hh2, W_l1, b_l1, W_l2, b_l2, outp);
}